// Round 19
// baseline (109.486 us; speedup 1.0000x reference)
//
#include <hip/hip_runtime.h>

// Chamfer distance, MFMA + EXACT spatial pruning. B=8, N=M=8192.
// 1) Counting-sort both clouds by 15-bit Morton cell (32^3 over [-5.5,5.5]^3).
// 2) Tile bboxes (32 sorted points/tile, 256 tiles/batch/cloud).
// 3) Main: R17-proven MFMA machinery (mfma4 VGPR-dest + s_nop hazard cover,
//    asm v_min3 consume) but each 64-row wave sweeps ONLY col-tiles whose
//    bbox lower-bound distance <= UB + margin. UB = min-over-lanes of
//    max-over-regs of rm (provably >= max over rows of current row-min).
//    Margin 0.125 >> 8x the 0.016 bf16-hi/lo D error -> pruning exact.
// 4) Row results scattered to original point order via perm.

typedef unsigned int uint;
typedef unsigned short ushort;
typedef unsigned long long ull;
typedef __attribute__((ext_vector_type(8))) short short8;
typedef __attribute__((ext_vector_type(16))) float f32x16;

#define B_     8
#define N_     8192
#define BN     (B_ * N_)        // 65536
#define CELLS  32768            // 32^3 Morton cells
#define TILES  256              // per batch per cloud (8192/32)
#define RPW    64
#define WAVES  4
#define RPB    (RPW * WAVES)    // 256 rows per block
#define RBLK   (N_ / RPB)       // 32
#define MARGIN 0.125f

// ---------- proven inner machinery (R16/R17) ----------
__device__ __forceinline__ void mfma4(const short8 a0, const short8 a1,
                                      const short8 q0, const short8 q1,
                                      const f32x16 zc,
                                      f32x16& d00, f32x16& d01,
                                      f32x16& d10, f32x16& d11) {
    asm volatile(
        "v_mfma_f32_32x32x16_bf16 %0, %4, %6, %8\n\t"
        "v_mfma_f32_32x32x16_bf16 %1, %4, %7, %8\n\t"
        "v_mfma_f32_32x32x16_bf16 %2, %5, %6, %8\n\t"
        "v_mfma_f32_32x32x16_bf16 %3, %5, %7, %8\n\t"
        "s_nop 7\n\t"
        "s_nop 7\n\t"
        "s_nop 7"
        : "=&v"(d00), "=&v"(d01), "=&v"(d10), "=&v"(d11)
        : "v"(a0), "v"(a1), "v"(q0), "v"(q1), "v"(zc));
}
__device__ __forceinline__ void consume16(f32x16& rm, const f32x16& d, const f32x16& e) {
#pragma unroll
    for (int k = 0; k < 16; ++k) {
        float r;
        asm("v_min3_f32 %0, %2, %3, %1"
            : "=v"(r) : "v"(rm[k]), "v"(d[k]), "v"(e[k]));
        rm[k] = r;
    }
}
__device__ __forceinline__ void sweep_pair(const short8* __restrict__ bpBase, int tc,
                                           const short8 a0, const short8 a1,
                                           const f32x16& zc, f32x16& rm0, f32x16& rm1) {
    short8 q0 = bpBase[tc * 64];
    short8 q1 = bpBase[tc * 64 + 64];
    f32x16 d00, d01, d10, d11;
    mfma4(a0, a1, q0, q1, zc, d00, d01, d10, d11);
    consume16(rm0, d00, d01);
    consume16(rm1, d10, d11);
}

__device__ __forceinline__ ushort f2bf(float f) {
    uint u = __float_as_uint(f);
    return (ushort)((u + 0x7FFFu + ((u >> 16) & 1u)) >> 16);
}
__device__ __forceinline__ float bf2f(ushort h) {
    return __uint_as_float(((uint)h) << 16);
}
__device__ __forceinline__ short8 build_a(const float* __restrict__ own, int g, int h) {
    float x = own[3 * g], y = own[3 * g + 1], z = own[3 * g + 2];
    float s = fmaf(x, x, fmaf(y, y, z * z));
    ushort xh = f2bf(x), xl = f2bf(x - bf2f(xh));
    ushort yh = f2bf(y), yl = f2bf(y - bf2f(yh));
    ushort zh = f2bf(z), zl = f2bf(z - bf2f(zh));
    ushort sh = f2bf(s), sl = f2bf(s - bf2f(sh));
    const ushort one = 0x3F80;
    short8 a;
    a[0] = (short)(h ? zl  : xh);
    a[1] = (short)(h ? one : xh);
    a[2] = (short)(h ? one : xl);
    a[3] = (short)(h ? sh  : yh);
    a[4] = (short)(h ? sl  : yh);
    a[5] = (short)(h ? 0   : yl);
    a[6] = (short)(h ? 0   : zh);
    a[7] = (short)(h ? 0   : zh);
    return a;
}

// ---------- Morton binning ----------
__device__ __forceinline__ uint spread5(uint v) {
    return (v & 1u) | ((v & 2u) << 2) | ((v & 4u) << 4) |
           ((v & 8u) << 6) | ((v & 16u) << 8);
}
__device__ __forceinline__ int cell_of(float x, float y, float z) {
    int cx = (int)((x + 5.5f) * (32.0f / 11.0f));
    int cy = (int)((y + 5.5f) * (32.0f / 11.0f));
    int cz = (int)((z + 5.5f) * (32.0f / 11.0f));
    cx = min(31, max(0, cx)); cy = min(31, max(0, cy)); cz = min(31, max(0, cz));
    return (int)(spread5((uint)cx) | (spread5((uint)cy) << 1) | (spread5((uint)cz) << 2));
}

// grid (BN/256, 2): histogram of cells per (cloud,batch).
__global__ void bin_count(const float* __restrict__ x1, const float* __restrict__ x2,
                          uint* __restrict__ hist) {
    int cloud = blockIdx.y;
    int gi = blockIdx.x * 256 + threadIdx.x;
    int b = gi >> 13;
    const float* xyz = cloud ? x2 : x1;
    int cell = cell_of(xyz[3 * gi], xyz[3 * gi + 1], xyz[3 * gi + 2]);
    atomicAdd(&hist[(size_t)(cloud * 8 + b) * CELLS + cell], 1u);
}

// 16 blocks (one per cloud*batch), 256 threads: in-place exclusive scan.
__global__ void scan_k(uint* __restrict__ hist) {
    __shared__ uint ps[256];
    uint* h = hist + (size_t)blockIdx.x * CELLS;
    int t = threadIdx.x;
    uint s = 0;
    for (int j = 0; j < 128; ++j) s += h[t * 128 + j];
    ps[t] = s;
    __syncthreads();
    if (t == 0) {
        uint run = 0;
        for (int i = 0; i < 256; ++i) { uint tmp = ps[i]; ps[i] = run; run += tmp; }
    }
    __syncthreads();
    uint run = ps[t];
    for (int j = 0; j < 128; ++j) { uint tmp = h[t * 128 + j]; h[t * 128 + j] = run; run += tmp; }
}

// grid (BN/256, 2): scatter points to sorted order; record perm (orig local id).
__global__ void scatter_k(const float* __restrict__ x1, const float* __restrict__ x2,
                          uint* __restrict__ hist,
                          float* __restrict__ x1r, float* __restrict__ x2r,
                          int* __restrict__ perm) {
    int cloud = blockIdx.y;
    int gi = blockIdx.x * 256 + threadIdx.x;
    int b = gi >> 13, local = gi & 8191;
    const float* xyz = cloud ? x2 : x1;
    float x = xyz[3 * gi], y = xyz[3 * gi + 1], z = xyz[3 * gi + 2];
    int cell = cell_of(x, y, z);
    uint pos = atomicAdd(&hist[(size_t)(cloud * 8 + b) * CELLS + cell], 1u);
    float* dst = cloud ? x2r : x1r;
    size_t di = (size_t)b * 8192 + pos;
    dst[3 * di] = x; dst[3 * di + 1] = y; dst[3 * di + 2] = z;
    perm[(size_t)cloud * BN + di] = local;
}

// grid (BN/256, 2): pack reordered points to col-form + tile bboxes.
__global__ void pack_bbox(const float* __restrict__ x1r, const float* __restrict__ x2r,
                          ushort* __restrict__ Bv1, ushort* __restrict__ Bv2,
                          float* __restrict__ bbox) {
    int cloud = blockIdx.y;
    int gi = blockIdx.x * 256 + threadIdx.x;
    const float* src = cloud ? x2r : x1r;
    float x = src[3 * gi], y = src[3 * gi + 1], z = src[3 * gi + 2];
    float s = fmaf(x, x, fmaf(y, y, z * z));
    float sx = -2.0f * x, sy = -2.0f * y, sz = -2.0f * z;
    ushort xh = f2bf(sx), xl = f2bf(sx - bf2f(xh));
    ushort yh = f2bf(sy), yl = f2bf(sy - bf2f(yh));
    ushort zh = f2bf(sz), zl = f2bf(sz - bf2f(zh));
    ushort sh = f2bf(s),  sl = f2bf(s - bf2f(sh));
    const uint one = 0x3F80u;
    ushort* vec = cloud ? Bv2 : Bv1;
    uint4* dst = (uint4*)(vec + (size_t)gi * 16);
    dst[0] = make_uint4((uint)xh | ((uint)xl << 16), (uint)xh | ((uint)yh << 16),
                        (uint)yl | ((uint)yh << 16), (uint)zh | ((uint)zl << 16));
    dst[1] = make_uint4((uint)zh | ((uint)sh << 16), (uint)sl | (one << 16), one, 0u);
    // tile bbox: reduce over the 32 threads of this tile (same half-wave)
    float mnx = x, mxx = x, mny = y, mxy = y, mnz = z, mxz = z;
#pragma unroll
    for (int sft = 16; sft >= 1; sft >>= 1) {
        mnx = fminf(mnx, __shfl_xor(mnx, sft)); mxx = fmaxf(mxx, __shfl_xor(mxx, sft));
        mny = fminf(mny, __shfl_xor(mny, sft)); mxy = fmaxf(mxy, __shfl_xor(mxy, sft));
        mnz = fminf(mnz, __shfl_xor(mnz, sft)); mxz = fmaxf(mxz, __shfl_xor(mxz, sft));
    }
    if ((threadIdx.x & 31) == 0) {
        float* bb = bbox + (size_t)(cloud * 2048 + (gi >> 5)) * 6;
        bb[0] = mnx; bb[1] = mny; bb[2] = mnz; bb[3] = mxx; bb[4] = mxy; bb[5] = mxz;
    }
}

__device__ __forceinline__ float lb_of(const float* __restrict__ cb,
                                       float rmnx, float rmny, float rmnz,
                                       float rmxx, float rmxy, float rmxz) {
    float dx = fmaxf(0.0f, fmaxf(cb[0] - rmxx, rmnx - cb[3]));
    float dy = fmaxf(0.0f, fmaxf(cb[1] - rmxy, rmny - cb[4]));
    float dz = fmaxf(0.0f, fmaxf(cb[2] - rmxz, rmnz - cb[5]));
    return fmaf(dx, dx, fmaf(dy, dy, dz * dz));
}

// grid = (B_*RBLK, 2) = (256, 2). 4 waves/block, 64 rows/wave, pruned sweep.
__global__ __launch_bounds__(256, 2)
void cham_prune(const float* __restrict__ x1r, const float* __restrict__ x2r,
                const short8* __restrict__ Bv1, const short8* __restrict__ Bv2,
                const float* __restrict__ bbox, const int* __restrict__ perm,
                float* __restrict__ out) {
    const int tid  = threadIdx.x;
    const int wave = tid >> 6;
    const int lane = tid & 63;
    const int half = lane >> 5;
    const int lc   = lane & 31;

    const int b   = blockIdx.x / RBLK;
    const int rb  = blockIdx.x % RBLK;
    const int dir = blockIdx.y;            // 0: rows=cloud1 cols=cloud2

    const float*  own = dir ? x2r : x1r;   // rows (reordered)
    const short8* Bv  = dir ? Bv1 : Bv2;   // cols (other cloud, packed)

    const int row0 = rb * RPB + wave * RPW;   // within batch, reordered domain
    const int gq   = b * 8192 + row0;

    const short8 a0 = build_a(own, gq + lc, half);
    const short8 a1 = build_a(own, gq + 32 + lc, half);

    // wave row-bbox = union of its 2 row-tiles
    const int rtile = row0 >> 5;
    const float* rbb = bbox + (size_t)(dir * 2048 + b * TILES + rtile) * 6;
    float rmnx = fminf(rbb[0], rbb[6]),  rmny = fminf(rbb[1], rbb[7]);
    float rmnz = fminf(rbb[2], rbb[8]);
    float rmxx = fmaxf(rbb[3], rbb[9]),  rmxy = fmaxf(rbb[4], rbb[10]);
    float rmxz = fmaxf(rbb[5], rbb[11]);

    // per-lane lower bounds for col-tiles 4*lane .. 4*lane+3
    const float* cbb = bbox + (size_t)((dir ^ 1) * 2048 + b * TILES + 4 * lane) * 6;
    float lb0 = lb_of(cbb + 0,  rmnx, rmny, rmnz, rmxx, rmxy, rmxz);
    float lb1 = lb_of(cbb + 6,  rmnx, rmny, rmnz, rmxx, rmxy, rmxz);
    float lb2 = lb_of(cbb + 12, rmnx, rmny, rmnz, rmxx, rmxy, rmxz);
    float lb3 = lb_of(cbb + 18, rmnx, rmny, rmnz, rmxx, rmxy, rmxz);

    f32x16 zc;
#pragma unroll
    for (int k = 0; k < 16; ++k) zc[k] = 0.0f;
    f32x16 rm0, rm1;
#pragma unroll
    for (int k = 0; k < 16; ++k) { rm0[k] = 3.0e38f; rm1[k] = 3.0e38f; }

    const short8* bpBase = Bv + ((size_t)b * 8192 + lc) * 2 + half;

    // bootstrap: sweep the globally-closest tile pair
    float bv = lb0; int bi = 4 * lane;
    if (lb1 < bv) { bv = lb1; bi = 4 * lane + 1; }
    if (lb2 < bv) { bv = lb2; bi = 4 * lane + 2; }
    if (lb3 < bv) { bv = lb3; bi = 4 * lane + 3; }
#pragma unroll
    for (int s = 32; s >= 1; s >>= 1) {
        float ov = __shfl_xor(bv, s); int oi = __shfl_xor(bi, s);
        if (ov < bv || (ov == bv && oi < bi)) { bv = ov; bi = oi; }
    }
    sweep_pair(bpBase, bi & ~1, a0, a1, zc, rm0, rm1);

    // UB bound: min over lanes of (max over regs) >= max over rows of row-min
    float Q = rm0[0];
#pragma unroll
    for (int k = 1; k < 16; ++k) Q = fmaxf(Q, rm0[k]);
#pragma unroll
    for (int k = 0; k < 16; ++k) Q = fmaxf(Q, rm1[k]);
#pragma unroll
    for (int s = 32; s >= 1; s >>= 1) Q = fminf(Q, __shfl_xor(Q, s));
    const float UBm = Q + MARGIN;

    // candidate masks (per lane owns 2 tile-pairs), uniform bit-scan sweep
    ull mA = __ballot(fminf(lb0, lb1) <= UBm);
    ull mB = __ballot(fminf(lb2, lb3) <= UBm);
    while (mA) { int g = __ffsll(mA) - 1; mA &= mA - 1;
                 sweep_pair(bpBase, 4 * g,     a0, a1, zc, rm0, rm1); }
    while (mB) { int g = __ffsll(mB) - 1; mB &= mB - 1;
                 sweep_pair(bpBase, 4 * g + 2, a0, a1, zc, rm0, rm1); }

    // butterfly row-min across the 32 col-lanes of each half-group
#pragma unroll
    for (int k = 0; k < 16; ++k) {
#pragma unroll
        for (int s = 16; s >= 1; s >>= 1) {
            rm0[k] = fminf(rm0[k], __shfl_xor(rm0[k], s));
            rm1[k] = fminf(rm1[k], __shfl_xor(rm1[k], s));
        }
    }

    // store to ORIGINAL row order via perm. C layout row = (k&3)+8*(k>>2)+4*half.
    if (lc == 0) {
        const int* pm = perm + (size_t)dir * BN + (size_t)b * 8192;
        float* o = out + (size_t)dir * BN + (size_t)b * 8192;
#pragma unroll
        for (int k = 0; k < 16; ++k) {
            int rr = (k & 3) + 8 * (k >> 2) + 4 * half;
            o[pm[row0 + rr]]      = rm0[k];
            o[pm[row0 + 32 + rr]] = rm1[k];
        }
    }
}

extern "C" void kernel_launch(void* const* d_in, const int* in_sizes, int n_in,
                              void* d_out, int out_size, void* d_ws, size_t ws_size,
                              hipStream_t stream) {
    const float* xyz1 = (const float*)d_in[0];
    const float* xyz2 = (const float*)d_in[1];
    float* out = (float*)d_out;

    // ws layout (peak 6.1 MB; 8 MB proven available in R11):
    char* w = (char*)d_ws;
    float* x1r  = (float*)(w);                       // 786432 B
    float* x2r  = (float*)(w + 786432);              // 786432 B
    int*   perm = (int*)  (w + 1572864);             // 524288 B
    float* bbox = (float*)(w + 2097152);             // 98304 B
    uint*  hist = (uint*) (w + 2195456);             // 2 MB (reused as Bv1)
    ushort* Bv1 = (ushort*)(w + 2195456);            // aliases hist (hist dead)
    ushort* Bv2 = (ushort*)(w + 4292608);            // 2 MB

    hipMemsetAsync(hist, 0, (size_t)16 * CELLS * 4, stream);

    dim3 g2(BN / 256, 2);
    bin_count<<<g2, 256, 0, stream>>>(xyz1, xyz2, hist);
    scan_k<<<16, 256, 0, stream>>>(hist);
    scatter_k<<<g2, 256, 0, stream>>>(xyz1, xyz2, hist, x1r, x2r, perm);
    pack_bbox<<<g2, 256, 0, stream>>>(x1r, x2r, Bv1, Bv2, bbox);  // Bv1 overwrites dead hist

    dim3 grid(B_ * RBLK, 2);   // (256, 2)
    cham_prune<<<grid, 256, 0, stream>>>(x1r, x2r, (const short8*)Bv1, (const short8*)Bv2,
                                         bbox, perm, out);
}

// Round 20
// 60.632 us; speedup vs baseline: 1.8057x; 1.8057x over previous
//
#include <hip/hip_runtime.h>

// Chamfer distance via MFMA, two-pass row-min, B=8, N=M=8192.
// D[i,j] = sq_i + sq_j - 2<pi,pj> as one K=16 bf16 dot (hi/lo split, fp32-class):
//   A row-form: [xh,xh,xl, yh,yh,yl, zh,zh,zl, 1,1, sh,sl, 0,0,0]  (built in-kernel)
//   B col-form: [Xh,Xl,Xh, Yh,Yl,Yh, Zh,Zl,Zh, Sh,Sl, 1,1, 0,0,0]  (-2 on coords)
// R20 = R9's proven kernel with SPLITJ=1: each wave sweeps ALL 8192 cols, so
// there are no j-split partials and no decode kernel — blocks own unique
// output rows and store directly to out. 2 launches total (prep + main).

typedef unsigned int uint;
typedef unsigned short ushort;
typedef __attribute__((ext_vector_type(8))) short short8;
typedef __attribute__((ext_vector_type(16))) float f32x16;

#define B_     8
#define N_     8192
#define M_     8192
#define BN     (B_ * N_)        // 65536
#define JT     (M_ / 32)        // 256 col-tiles (full sweep)
#define RPW    64               // rows per wave (2 A-frags)
#define WAVES  4
#define RPB    (RPW * WAVES)    // 256 rows per block
#define RBLK   (N_ / RPB)       // 32 row-blocks per batch

__device__ __forceinline__ ushort f2bf(float f) {   // RNE f32->bf16
    uint u = __float_as_uint(f);
    return (ushort)((u + 0x7FFFu + ((u >> 16) & 1u)) >> 16);
}
__device__ __forceinline__ float bf2f(ushort h) {
    return __uint_as_float(((uint)h) << 16);
}

// Col-form pack for both clouds in one launch (coords scaled by -2, sq unscaled).
// grid = (BN/256, 2)
__global__ void prep_kernel(const float* __restrict__ x1, const float* __restrict__ x2,
                            ushort* __restrict__ v1, ushort* __restrict__ v2) {
    int i = blockIdx.x * 256 + threadIdx.x;
    const float* __restrict__ xyz = blockIdx.y ? x2 : x1;
    ushort* __restrict__ vec = blockIdx.y ? v2 : v1;
    float x = xyz[3 * i], y = xyz[3 * i + 1], z = xyz[3 * i + 2];
    float s = fmaf(x, x, fmaf(y, y, z * z));
    x *= -2.0f; y *= -2.0f; z *= -2.0f;
    ushort xh = f2bf(x), xl = f2bf(x - bf2f(xh));
    ushort yh = f2bf(y), yl = f2bf(y - bf2f(yh));
    ushort zh = f2bf(z), zl = f2bf(z - bf2f(zh));
    ushort sh = f2bf(s), sl = f2bf(s - bf2f(sh));
    const uint one = 0x3F80u;
    uint4* dst = (uint4*)(vec + (size_t)i * 16);
    dst[0] = make_uint4((uint)xh | ((uint)xl << 16), (uint)xh | ((uint)yh << 16),
                        (uint)yl | ((uint)yh << 16), (uint)zh | ((uint)zl << 16));
    dst[1] = make_uint4((uint)zh | ((uint)sh << 16), (uint)sl | (one << 16),
                        one, 0u);
}

// Build A row-frag for global row g, k-half h, from raw xyz.
__device__ __forceinline__ short8 build_a(const float* __restrict__ own, int g, int h) {
    float x = own[3 * g], y = own[3 * g + 1], z = own[3 * g + 2];
    float s = fmaf(x, x, fmaf(y, y, z * z));
    ushort xh = f2bf(x), xl = f2bf(x - bf2f(xh));
    ushort yh = f2bf(y), yl = f2bf(y - bf2f(yh));
    ushort zh = f2bf(z), zl = f2bf(z - bf2f(zh));
    ushort sh = f2bf(s), sl = f2bf(s - bf2f(sh));
    const ushort one = 0x3F80;
    short8 a;
    a[0] = (short)(h ? zl  : xh);
    a[1] = (short)(h ? one : xh);
    a[2] = (short)(h ? one : xl);
    a[3] = (short)(h ? sh  : yh);
    a[4] = (short)(h ? sl  : yh);
    a[5] = (short)(h ? 0   : yl);
    a[6] = (short)(h ? 0   : zh);
    a[7] = (short)(h ? 0   : zh);
    return a;
}

// grid = (B_*RBLK, 2) = (256, 2). 4 waves/block, 64 rows/wave, full col sweep.
__global__ __launch_bounds__(256, 4)
void cham_mfma14(const float* __restrict__ xyz1, const float* __restrict__ xyz2,
                 const short8* __restrict__ Bv1,  // col-form pack of cloud1
                 const short8* __restrict__ Bv2,  // col-form pack of cloud2
                 float* __restrict__ out) {       // [2][BN] final distances
    const int tid  = threadIdx.x;
    const int wave = tid >> 6;
    const int lane = tid & 63;
    const int half = lane >> 5;
    const int lc   = lane & 31;

    const int b   = blockIdx.x / RBLK;
    const int rb  = blockIdx.x % RBLK;
    const int dir = blockIdx.y;

    const float*  own = dir ? xyz2 : xyz1;   // rows from this cloud
    const short8* Bv  = dir ? Bv1  : Bv2;    // sweep the other cloud

    const int row0 = rb * RPB + wave * RPW;
    const int gr   = b * N_ + row0;

    const short8 a0 = build_a(own, gr + lc, half);
    const short8 a1 = build_a(own, gr + 32 + lc, half);

    f32x16 zc;
#pragma unroll
    for (int k = 0; k < 16; ++k) zc[k] = 0.0f;
    f32x16 rm0, rm1;
#pragma unroll
    for (int k = 0; k < 16; ++k) { rm0[k] = 3.0e38f; rm1[k] = 3.0e38f; }

    const short8* bp = Bv + ((size_t)b * M_ + lc) * 2 + half;

    // --- 2-tile-ahead register prefetch (named buffers, static indices) ---
    short8 qa0 = bp[0];
    short8 qa1 = bp[64];

    for (int t = 0; t < JT - 2; t += 2) {
        short8 qb0 = bp[(t + 2) * 64];          // issue next pair's loads first
        short8 qb1 = bp[(t + 3) * 64];
        f32x16 d00 = __builtin_amdgcn_mfma_f32_32x32x16_bf16(a0, qa0, zc, 0, 0, 0);
        f32x16 d01 = __builtin_amdgcn_mfma_f32_32x32x16_bf16(a0, qa1, zc, 0, 0, 0);
#pragma unroll
        for (int k = 0; k < 16; ++k)
            rm0[k] = fminf(fminf(d00[k], d01[k]), rm0[k]);   // min3-fusable
        f32x16 d10 = __builtin_amdgcn_mfma_f32_32x32x16_bf16(a1, qa0, zc, 0, 0, 0);
        f32x16 d11 = __builtin_amdgcn_mfma_f32_32x32x16_bf16(a1, qa1, zc, 0, 0, 0);
#pragma unroll
        for (int k = 0; k < 16; ++k)
            rm1[k] = fminf(fminf(d10[k], d11[k]), rm1[k]);
        qa0 = qb0;
        qa1 = qb1;
    }
    {   // last tile-pair (tiles JT-2, JT-1), already in qa0/qa1
        f32x16 d00 = __builtin_amdgcn_mfma_f32_32x32x16_bf16(a0, qa0, zc, 0, 0, 0);
        f32x16 d01 = __builtin_amdgcn_mfma_f32_32x32x16_bf16(a0, qa1, zc, 0, 0, 0);
        f32x16 d10 = __builtin_amdgcn_mfma_f32_32x32x16_bf16(a1, qa0, zc, 0, 0, 0);
        f32x16 d11 = __builtin_amdgcn_mfma_f32_32x32x16_bf16(a1, qa1, zc, 0, 0, 0);
#pragma unroll
        for (int k = 0; k < 16; ++k) {
            rm0[k] = fminf(fminf(d00[k], d01[k]), rm0[k]);
            rm1[k] = fminf(fminf(d10[k], d11[k]), rm1[k]);
        }
    }

    // Butterfly min across the 32 col-lanes of each half-group.
#pragma unroll
    for (int k = 0; k < 16; ++k) {
#pragma unroll
        for (int s2 = 16; s2 >= 1; s2 >>= 1) {
            rm0[k] = fminf(rm0[k], __shfl_xor(rm0[k], s2));
            rm1[k] = fminf(rm1[k], __shfl_xor(rm1[k], s2));
        }
    }

    // C layout: row = (k&3) + 8*(k>>2) + 4*half, col = lane&31.
    float* o = out + (size_t)dir * BN + gr;
    if (lc == 0) {
#pragma unroll
        for (int k = 0; k < 16; ++k) {
            int rr = (k & 3) + 8 * (k >> 2) + 4 * half;
            o[rr]      = rm0[k];
            o[32 + rr] = rm1[k];
        }
    }
}

extern "C" void kernel_launch(void* const* d_in, const int* in_sizes, int n_in,
                              void* d_out, int out_size, void* d_ws, size_t ws_size,
                              hipStream_t stream) {
    const float* xyz1 = (const float*)d_in[0];
    const float* xyz2 = (const float*)d_in[1];
    float* out = (float*)d_out;

    // ws: Bv1 (2MB) | Bv2 (2MB)
    ushort* Bv1 = (ushort*)d_ws;
    ushort* Bv2 = Bv1 + (size_t)BN * 16;

    dim3 pgrid(BN / 256, 2);
    prep_kernel<<<pgrid, 256, 0, stream>>>(xyz1, xyz2, Bv1, Bv2);

    dim3 grid(B_ * RBLK, 2);   // (256, 2)
    cham_mfma14<<<grid, 256, 0, stream>>>(xyz1, xyz2,
                                          (const short8*)Bv1, (const short8*)Bv2, out);
}